// Round 11
// baseline (62.395 us; speedup 1.0000x reference)
//
#include <hip/hip_runtime.h>
#include <hip/hip_bf16.h>

// Problem: B=16384, I=512, H=512.
// Output = modrelu(complex(inputs@w_ih.T [:, :512], [:, 512:]), b_h)
// The FFT/reflect/perm state path in the reference is DEAD CODE (preact unused).
//
// R11: single fused GEMM with 2-period-deep pipeline.
//  - A read as f32, cvt_pk in-register, swizzled ds_write (no A-cvt pass).
//  - B bf16 (tiny cvt_w pass) via global_load_lds, TRIPLE-buffered, staged
//    2 iters ahead.
//  - FIFO-derived counted vmcnt: top-of-iter vmcnt(12) drains only A(kt+1)
//    (issued 2 iters ago); end-of-iter vmcnt(20) drains only B(kt+1) (oldest).
//  - One barrier per iter. LDS 80KB -> 2 blocks/CU; C-tile epilogue aliases.

typedef __attribute__((ext_vector_type(8))) short bf16x8;
typedef __attribute__((ext_vector_type(4))) float f32x4;

#define BM 128            // M rows per block
#define BK 64             // K per tile
#define KDIM 512
#define NDIM 1024
#define NKT 8

#define VMCNT(n) asm volatile("s_waitcnt vmcnt(" #n ")" ::: "memory")
#define LGKM(n)  asm volatile("s_waitcnt lgkmcnt(" #n ")" ::: "memory")

__device__ __forceinline__ unsigned short f2bf(float f) {
    unsigned u = __builtin_bit_cast(unsigned, f);
    u += 0x7fffu + ((u >> 16) & 1u);   // round-to-nearest-even
    return (unsigned short)(u >> 16);
}

__global__ __launch_bounds__(256) void cvt_w(const float* __restrict__ W,
                                             unsigned short* __restrict__ Wbf, int n4) {
    int i = blockIdx.x * blockDim.x + threadIdx.x;
    int stride = gridDim.x * blockDim.x;
    for (; i < n4; i += stride) {
        float4 v = reinterpret_cast<const float4*>(W)[i];
        ushort4 o;
        o.x = f2bf(v.x); o.y = f2bf(v.y); o.z = f2bf(v.z); o.w = f2bf(v.w);
        reinterpret_cast<ushort4*>(Wbf)[i] = o;
    }
}

__device__ __forceinline__ void gload_lds16(const void* g, void* l) {
    __builtin_amdgcn_global_load_lds(
        (const __attribute__((address_space(1))) unsigned int*)g,
        (__attribute__((address_space(3))) unsigned int*)l, 16, 0, 0);
}

__device__ __forceinline__ unsigned cvtpk(float lo, float hi) {
    unsigned r;
    asm("v_cvt_pk_bf16_f32 %0, %1, %2" : "=v"(r) : "v"(lo), "v"(hi));
    return r;
}

// 128 M-rows x 64 re/im col-pairs per block. 4 waves 2M x 2N; per wave
// 64 rows x 32 pairs: acc[4][4] (j 0..1 re, j 2..3 im).
// B-tile rows 0..63 = W[cb*64+r] (re), 64..127 = W[512+cb*64+r] (im).
__global__ __launch_bounds__(256) void gemm_modrelu(
    const float* __restrict__ A,            // 16384 x 512 f32
    const unsigned short* __restrict__ W,   // 1024 x 512 bf16
    const float* __restrict__ bh,           // 512 f32
    float* __restrict__ out)                // 16384 x 1024 f32
{
    // bufA[2] @ 0,16384 ; bufB[3] @ 32768,49152,65536 (each 16 KB). 80 KB total.
    // Epilogue C (128x128 f32, 64 KB) aliases [0, 65536).
    __shared__ __align__(16) char smem[81920];
    unsigned short* At0 = (unsigned short*)smem;            // [2][8192] shorts
    unsigned short* Bt0 = (unsigned short*)(smem + 32768);  // [3][8192] shorts
    float* C = (float*)smem;                                // [128][128]

    const int tid = threadIdx.x;
    const int w   = tid >> 6;
    const int l   = tid & 63;
    const int l15 = l & 15;
    const int l4  = l >> 4;
    const int wm  = w >> 1;        // 0..1 : 64-row half
    const int wn  = w & 1;         // 0..1 : 32-pair half

    // T1: XCD-chunked swizzle. 1024 blocks, 128/XCD, cb fastest: the 8 sharers
    // of each A panel run on one XCD.
    const int bx = blockIdx.x;
    const int lg = (bx & 7) * 128 + (bx >> 3);
    const int mb = lg >> 3;        // 128 m-blocks of 128 rows
    const int cb = lg & 7;         // 8 col-blocks of 64 pairs

    // ---- A f32 -> reg -> bf16 -> swizzled LDS (verified in R5) ----
    // 8 sweeps: row = s*16 + (tid>>4); float4 seg = tid&15 (16 f4/row of 64 K).
    const int arow0 = tid >> 4;          // 0..15
    const int aseg  = tid & 15;          // 0..15
    const int awoff = (aseg * 4) ^ ((arow0 & 7) << 3);   // swizzled short offset
    const float4* gA = reinterpret_cast<const float4*>(A) + (size_t)(mb * BM) * (KDIM / 4);

    // ---- B staging (gload_lds, pre-swizzled source; verified R10) ----
    const int srow = l >> 3;
    const int sseg = (l & 7) ^ srow;
    const unsigned short* gb[4];
    int ldsoB[4];
#pragma unroll
    for (int is = 0; is < 4; ++is) {
        int row   = w * 32 + is * 8 + srow;
        int wrow  = (row >> 6) * 512 + cb * 64 + (row & 63);
        gb[is]    = W + (size_t)wrow * KDIM + sseg * 8;
        ldsoB[is] = (w * 32 + is * 8) * BK;   // wave-uniform LDS base (shorts)
    }

    float4 ra[3][8];
    auto load_a = [&](int kt, int set) {
#pragma unroll
        for (int s = 0; s < 8; ++s)
            ra[set][s] = gA[(size_t)(s * 16 + arow0) * (KDIM / 4) + kt * (BK / 4) + aseg];
    };
    auto write_a = [&](int buf, int set) {
#pragma unroll
        for (int s = 0; s < 8; ++s) {
            uint2 o;
            o.x = cvtpk(ra[set][s].x, ra[set][s].y);
            o.y = cvtpk(ra[set][s].z, ra[set][s].w);
            *reinterpret_cast<uint2*>(&At0[buf * 8192 + (s * 16 + arow0) * BK + awoff]) = o;
        }
    };
    auto stage_b = [&](int kt, int bi) {
#pragma unroll
        for (int is = 0; is < 4; ++is)
            gload_lds16(gb[is] + kt * BK, Bt0 + bi * 8192 + ldsoB[is]);
    };

    f32x4 acc[4][4];
#pragma unroll
    for (int i = 0; i < 4; ++i)
#pragma unroll
        for (int j = 0; j < 4; ++j) acc[i][j] = f32x4{0.f, 0.f, 0.f, 0.f};

    // ---- prologue: establish steady FIFO [A(kt+1), B(kt+1), A(kt+2)] ----
    load_a(0, 0);      // A0:8
    stage_b(0, 0);     // B0:4
    load_a(1, 1);      // A1:8
    stage_b(1, 1);     // B1:4
    load_a(2, 2);      // A2:8   FIFO: A0 B0 A1 B1 A2 = 32
    VMCNT(20);         // drain A0 (regs) + B0 (LDS); leaves A1,B1,A2
    write_a(0, 0);
    LGKM(0);
    __syncthreads();

#pragma unroll
    for (int kt = 0; kt < NKT; ++kt) {
        const unsigned short* at = At0 + (kt & 1) * 8192;
        const unsigned short* bt = Bt0 + (kt % 3) * 8192;

        // top wait: drain A(kt+1) regs (issued 2 iters ago — near-free)
        if (kt <= 5)      { VMCNT(12); }
        else if (kt == 6) { VMCNT(4); }

        bf16x8 af[4], bfr[4];
        // ks0 fragment reads (granule slot = l4 ^ (row&7))
#pragma unroll
        for (int i = 0; i < 4; ++i) {
            int row = wm * 64 + i * 16 + l15;
            af[i] = *(const bf16x8*)(&at[row * BK + ((l4 ^ (row & 7)) * 8)]);
        }
#pragma unroll
        for (int j = 0; j < 4; ++j) {
            int row = (j >> 1) * 64 + wn * 32 + (j & 1) * 16 + l15;
            bfr[j] = *(const bf16x8*)(&bt[row * BK + ((l4 ^ (row & 7)) * 8)]);
        }
        // pipeline issues (2-period lookahead)
        if (kt + 1 < NKT) write_a((kt + 1) & 1, (kt + 1) % 3);
        if (kt + 2 < NKT) stage_b(kt + 2, (kt + 2) % 3);
        if (kt + 3 < NKT) load_a(kt + 3, (kt + 3) % 3);

        LGKM(0);
        __builtin_amdgcn_sched_barrier(0);
        __builtin_amdgcn_s_setprio(1);
#pragma unroll
        for (int i = 0; i < 4; ++i)
#pragma unroll
            for (int j = 0; j < 4; ++j)
                acc[i][j] = __builtin_amdgcn_mfma_f32_16x16x32_bf16(
                    af[i], bfr[j], acc[i][j], 0, 0, 0);
        __builtin_amdgcn_s_setprio(0);

        // ks1 fragment reads (granule slot = (4+l4) ^ (row&7))
#pragma unroll
        for (int i = 0; i < 4; ++i) {
            int row = wm * 64 + i * 16 + l15;
            af[i] = *(const bf16x8*)(&at[row * BK + (((4 + l4) ^ (row & 7)) * 8)]);
        }
#pragma unroll
        for (int j = 0; j < 4; ++j) {
            int row = (j >> 1) * 64 + wn * 32 + (j & 1) * 16 + l15;
            bfr[j] = *(const bf16x8*)(&bt[row * BK + (((4 + l4) ^ (row & 7)) * 8)]);
        }
        LGKM(0);
        __builtin_amdgcn_sched_barrier(0);
        __builtin_amdgcn_s_setprio(1);
#pragma unroll
        for (int i = 0; i < 4; ++i)
#pragma unroll
            for (int j = 0; j < 4; ++j)
                acc[i][j] = __builtin_amdgcn_mfma_f32_16x16x32_bf16(
                    af[i], bfr[j], acc[i][j], 0, 0, 0);
        __builtin_amdgcn_s_setprio(0);

        // end wait: drain B(kt+1) (oldest FIFO entry -> no forced A drain),
        // then barrier makes all waves' staged B / written A visible.
        if (kt <= 4)      { VMCNT(20); __builtin_amdgcn_s_barrier(); }
        else if (kt == 5) { VMCNT(12); __builtin_amdgcn_s_barrier(); }
        else if (kt == 6) { VMCNT(0);  __builtin_amdgcn_s_barrier(); }
        // kt == 7: fall through to epilogue syncthreads
    }

    // ---- fused modReLU + LDS-coalesced store epilogue (verified R10) ----
    // C/D layout (m89): col = lane&15 (n), row = (lane>>4)*4 + jj (m)
    __syncthreads();                               // K-loop LDS reads all done
#pragma unroll
    for (int j = 0; j < 2; ++j) {                  // pair fragments (re j, im j+2)
        int col = wn * 32 + j * 16 + l15;          // local pair index 0..63
        float b = bh[cb * 64 + col];
#pragma unroll
        for (int i = 0; i < 4; ++i) {
#pragma unroll
            for (int jj = 0; jj < 4; ++jj) {
                int rowl = wm * 64 + i * 16 + l4 * 4 + jj;
                float re  = acc[i][j][jj];
                float imv = acc[i][j + 2][jj];
                float norm  = sqrtf(re * re + imv * imv);
                float scale = fmaxf(norm + b, 0.f) * __builtin_amdgcn_rcpf(norm + 1e-6f);
                C[rowl * 128 + col]      = re  * scale;   // cols 0..63  = re
                C[rowl * 128 + 64 + col] = imv * scale;   // cols 64..127 = im
            }
        }
    }
    __syncthreads();

    // flat re-read: 32 lanes cover one 128-f32 C row (lanes 0..15 re, 16..31 im),
    // 2 rows per instruction -> contiguous 256B runs per half-row.
    const int seg   = l & 31;
    const int rhalf = l >> 5;
#pragma unroll
    for (int it = 0; it < 16; ++it) {
        int rowl = w * 32 + it * 2 + rhalf;
        f32x4 v = *reinterpret_cast<const f32x4*>(&C[rowl * 128 + seg * 4]);
        size_t m = (size_t)(mb * BM + rowl);
        int n = (seg < 16) ? (cb * 64 + seg * 4)
                           : (512 + cb * 64 + (seg - 16) * 4);
        *reinterpret_cast<f32x4*>(out + m * NDIM + n) = v;
    }
}

extern "C" void kernel_launch(void* const* d_in, const int* in_sizes, int n_in,
                              void* d_out, int out_size, void* d_ws, size_t ws_size,
                              hipStream_t stream) {
    const float* inputs = (const float*)d_in[0];   // (16384, 512) f32
    const float* w_ih   = (const float*)d_in[2];   // (1024, 512)  f32
    const float* b_h    = (const float*)d_in[3];   // (512,)       f32
    float* out = (float*)d_out;                    // (16384, 1024) f32

    unsigned short* Wbf = (unsigned short*)d_ws;   // 1 MiB

    cvt_w<<<256, 256, 0, stream>>>(w_ih, Wbf, (1024 * 512) / 4);

    // 128 m-blocks x 8 col-blocks = 1024 blocks, 2 resident/CU (80 KB LDS)
    gemm_modrelu<<<1024, 256, 0, stream>>>(inputs, Wbf, b_h, out);
}

// Round 12
// 43.746 us; speedup vs baseline: 1.4263x; 1.4263x over previous
//
#include <hip/hip_runtime.h>
#include <hip/hip_bf16.h>

// Problem: B=16384, I=512, H=512.
// Output = modrelu(complex(inputs@w_ih.T [:, :512], [:, 512:]), b_h)
// The FFT/reflect/perm state path in the reference is DEAD CODE (preact unused).
//
// R12: occupancy play. R8's proven counted-vmcnt dbuf loop with BK=32 ->
// 32KB LDS -> 4 blocks/CU (16 waves/CU). Direct plain stores (coalescing
// proven neutral R5-vs-R8-vs-R10). Two-pass cvt kept (fusion hurt: R4/R5/R11).

typedef __attribute__((ext_vector_type(8))) short bf16x8;
typedef __attribute__((ext_vector_type(4))) float f32x4;

#define BM 128            // M rows per block
#define BK 32             // K per tile
#define KDIM 512
#define NDIM 1024
#define NKT 16

#define VMCNT(n) asm volatile("s_waitcnt vmcnt(" #n ")" ::: "memory")
#define LGKM(n)  asm volatile("s_waitcnt lgkmcnt(" #n ")" ::: "memory")

__device__ __forceinline__ unsigned short f2bf(float f) {
    unsigned u = __builtin_bit_cast(unsigned, f);
    u += 0x7fffu + ((u >> 16) & 1u);   // round-to-nearest-even
    return (unsigned short)(u >> 16);
}

// single conversion dispatch for both A and W
__global__ __launch_bounds__(256) void cvt_both(
    const float* __restrict__ A, const float* __restrict__ W,
    unsigned short* __restrict__ Abf, unsigned short* __restrict__ Wbf,
    int nA4, int nTot4) {
    int i = blockIdx.x * blockDim.x + threadIdx.x;
    int stride = gridDim.x * blockDim.x;
    for (; i < nTot4; i += stride) {
        float4 v;
        if (i < nA4) v = reinterpret_cast<const float4*>(A)[i];
        else         v = reinterpret_cast<const float4*>(W)[i - nA4];
        ushort4 o;
        o.x = f2bf(v.x); o.y = f2bf(v.y); o.z = f2bf(v.z); o.w = f2bf(v.w);
        if (i < nA4) reinterpret_cast<ushort4*>(Abf)[i] = o;
        else         reinterpret_cast<ushort4*>(Wbf)[i - nA4] = o;
    }
}

__device__ __forceinline__ void gload_lds16(const void* g, void* l) {
    __builtin_amdgcn_global_load_lds(
        (const __attribute__((address_space(1))) unsigned int*)g,
        (__attribute__((address_space(3))) unsigned int*)l, 16, 0, 0);
}

// 128 M-rows x 64 re/im col-pairs per block. 4 waves 2M x 2N; per wave
// 64 rows x 32 pairs: acc[4][4] (j 0..1 re, j 2..3 im).
// B-tile rows 0..63 = W[cb*64+r] (re), 64..127 = W[512+cb*64+r] (im).
__global__ __launch_bounds__(256, 4) void gemm_modrelu(
    const unsigned short* __restrict__ A,   // 16384 x 512 bf16
    const unsigned short* __restrict__ W,   // 1024 x 512 bf16
    const float* __restrict__ bh,           // 512 f32
    float* __restrict__ out)                // 16384 x 1024 f32
{
    // 32 KiB LDS -> 4 blocks/CU (16 waves/CU).
    __shared__ __align__(16) unsigned short At0[2][BM * BK];  // 2 x 8 KiB
    __shared__ __align__(16) unsigned short Bt0[2][BM * BK];  // 2 x 8 KiB

    const int tid = threadIdx.x;
    const int w   = tid >> 6;
    const int l   = tid & 63;
    const int l15 = l & 15;
    const int l4  = l >> 4;
    const int wm  = w >> 1;        // 0..1 : 64-row half
    const int wn  = w & 1;         // 0..1 : 32-pair half

    // T1: XCD-chunked swizzle. 1024 blocks, 128/XCD, cb fastest: the 8 sharers
    // of each A panel run on one XCD (1 HBM fetch + 7 L2 hits).
    const int bx = blockIdx.x;
    const int lg = (bx & 7) * 128 + (bx >> 3);
    const int mb = lg >> 3;        // 128 m-blocks of 128 rows
    const int cb = lg & 7;         // 8 col-blocks of 64 pairs

    // ---- staging (BK=32: row = 32 shorts = 4 x 16B granules) ----
    // Each stage-issue: 64 lanes x 16B = 16 rows. Wave w covers rows
    // [w*32, w*32+32) in 2 issues. Lane l -> row_off l>>2, phys granule l&3;
    // T2 both-sides swizzle f(row) = (row>>1)&3 -> source granule pre-XORed.
    const int srow = l >> 2;                 // 0..15
    const int sseg = (l & 3) ^ ((l >> 3) & 3);
    const unsigned short* ga[2];
    const unsigned short* gb[2];
    int ldso[2];
#pragma unroll
    for (int is = 0; is < 2; ++is) {
        int row  = w * 32 + is * 16 + srow;
        ga[is]   = A + (size_t)(mb * BM + row) * KDIM + sseg * 8;
        int wrow = (row >> 6) * 512 + cb * 64 + (row & 63);
        gb[is]   = W + (size_t)wrow * KDIM + sseg * 8;
        ldso[is] = (w * 32 + is * 16) * BK;   // wave-uniform LDS base (shorts)
    }

    auto stage = [&](int kt, int buf) {
#pragma unroll
        for (int is = 0; is < 2; ++is)
            gload_lds16(ga[is] + kt * BK, &At0[buf][ldso[is]]);
#pragma unroll
        for (int is = 0; is < 2; ++is)
            gload_lds16(gb[is] + kt * BK, &Bt0[buf][ldso[is]]);
    };

    f32x4 acc[4][4];
#pragma unroll
    for (int i = 0; i < 4; ++i)
#pragma unroll
        for (int j = 0; j < 4; ++j) acc[i][j] = f32x4{0.f, 0.f, 0.f, 0.f};

    // prologue: tiles 0 and 1 in flight (4 vmem ops each)
    stage(0, 0);
    stage(1, 1);
    VMCNT(4);                       // tile 0 resident
    __builtin_amdgcn_s_barrier();

    // fragment read slot (granule): l4 ^ f(row), f(row)=(row>>1)&3 = (l15>>1)&3
    const int rslot = (l4 ^ ((l15 >> 1) & 3)) * 8;

#pragma unroll
    for (int kt = 0; kt < NKT; ++kt) {
        const int buf = kt & 1;

        bf16x8 af[4], bfr[4];
#pragma unroll
        for (int i = 0; i < 4; ++i) {
            int row = wm * 64 + i * 16 + l15;
            af[i] = *(const bf16x8*)(&At0[buf][row * BK + rslot]);
        }
#pragma unroll
        for (int j = 0; j < 4; ++j) {
            int row = (j >> 1) * 64 + wn * 32 + (j & 1) * 16 + l15;
            bfr[j] = *(const bf16x8*)(&Bt0[buf][row * BK + rslot]);
        }
        LGKM(0);
        __builtin_amdgcn_sched_barrier(0);
        __builtin_amdgcn_s_setprio(1);
#pragma unroll
        for (int i = 0; i < 4; ++i)
#pragma unroll
            for (int j = 0; j < 4; ++j)
                acc[i][j] = __builtin_amdgcn_mfma_f32_16x16x32_bf16(
                    af[i], bfr[j], acc[i][j], 0, 0, 0);
        __builtin_amdgcn_s_setprio(0);

        if (kt + 1 < NKT) {
            __builtin_amdgcn_s_barrier();          // all waves done reading buf
            if (kt + 2 < NKT) {
                stage(kt + 2, buf);                // overwrite buf with tile kt+2
                VMCNT(4);                          // tile kt+1 landed, kt+2 in flight
            } else {
                VMCNT(0);                          // tail: drain tile kt+1
            }
            __builtin_amdgcn_s_barrier();          // tile kt+1 visible to all
        }
    }

    // ---- fused modReLU epilogue (direct stores; coalescing proven neutral) ----
    // C/D layout (m89): col = lane&15 (n), row = (lane>>4)*4 + jj (m)
#pragma unroll
    for (int j = 0; j < 2; ++j) {
        int n = cb * 64 + wn * 32 + j * 16 + l15;
        float b = bh[n];
#pragma unroll
        for (int i = 0; i < 4; ++i) {
#pragma unroll
            for (int jj = 0; jj < 4; ++jj) {
                int m = mb * BM + wm * 64 + i * 16 + l4 * 4 + jj;
                float re  = acc[i][j][jj];
                float imv = acc[i][j + 2][jj];
                float norm  = sqrtf(re * re + imv * imv);
                float scale = fmaxf(norm + b, 0.f) * __builtin_amdgcn_rcpf(norm + 1e-6f);
                float* po = out + (size_t)m * NDIM + n;
                po[0]   = re  * scale;
                po[512] = imv * scale;
            }
        }
    }
}

extern "C" void kernel_launch(void* const* d_in, const int* in_sizes, int n_in,
                              void* d_out, int out_size, void* d_ws, size_t ws_size,
                              hipStream_t stream) {
    const float* inputs = (const float*)d_in[0];   // (16384, 512) f32
    const float* w_ih   = (const float*)d_in[2];   // (1024, 512)  f32
    const float* b_h    = (const float*)d_in[3];   // (512,)       f32
    float* out = (float*)d_out;                    // (16384, 1024) f32

    unsigned short* Abf = (unsigned short*)d_ws;                          // 16 MiB
    unsigned short* Wbf = (unsigned short*)((char*)d_ws + (size_t)16384 * 512 * 2);

    const int nA4 = (16384 * 512) / 4;
    const int nW4 = (1024 * 512) / 4;
    cvt_both<<<2048, 256, 0, stream>>>(inputs, w_ih, Abf, Wbf, nA4, nA4 + nW4);

    // 128 m-blocks x 8 col-blocks = 1024 blocks, 4 resident/CU (32 KB LDS)
    gemm_modrelu<<<1024, 256, 0, stream>>>(Abf, Wbf, b_h, out);
}